// Round 3
// baseline (204.856 us; speedup 1.0000x reference)
//
#include <hip/hip_runtime.h>

// PillarFeatureNet: linear(9->64, no bias) -> BN1d (training stats over B*Cout
// rows, P*N=64 cols) -> ReLU -> max over N.
//
// Stats via Gram trick: mean[j] = invBC * sum_b dot(wsum, v[b,j])
//                       E[x^2][j] = invBC * sum_b v^T G v,  G = W^T W (9x9)
//
// Round-3 change: all pillar reads go through LDS staging with coalesced
// float4 global loads (round-2 pattern was 8B/lane at stride-72 -> ~32 L1
// transactions per load inst, ~480 GB/s ceiling). Finalize merged into main.
//
// ws float layout:
//   [0,81)      G (9x9 row-major)
//   [81,90)     wsum
//   [96,1120)   8 shadow copies x 128 accumulator floats
//               copy s, feature j, t(0=acc1,1=acc2): 96 + s*128 + j*2 + t

#define EPS_BN 1e-5f

__global__ __launch_bounds__(64) void pfn_prep(const float* __restrict__ W,
                                               float* __restrict__ ws) {
    __shared__ float prod[64][90];
    const int o = threadIdx.x;  // 0..63
    float w[9];
#pragma unroll
    for (int c = 0; c < 9; ++c) w[c] = W[o * 9 + c];
#pragma unroll
    for (int c = 0; c < 9; ++c)
#pragma unroll
        for (int c2 = 0; c2 < 9; ++c2) prod[o][c * 9 + c2] = w[c] * w[c2];
#pragma unroll
    for (int c = 0; c < 9; ++c) prod[o][81 + c] = w[c];
    // zero the 8 shadow accumulator copies: 1024 floats
#pragma unroll
    for (int k = 0; k < 16; ++k) ws[96 + o * 16 + k] = 0.f;
    __syncthreads();
    for (int col = o; col < 90; col += 64) {
        float s = 0.f;
        for (int r = 0; r < 64; ++r) s += prod[r][col];
        ws[col] = s;
    }
}

// One 8-b tile per block. Coalesced float4 staging -> LDS, then per-lane
// 18-float rows from LDS. G/wsum read from LDS (uniform broadcast) to keep
// VGPRs low (whole grid resident).
__global__ __launch_bounds__(256) void pfn_stats(const float* __restrict__ pillars,
                                                 const float* __restrict__ gw,
                                                 float* __restrict__ acc8,
                                                 int ntiles) {
    __shared__ float4 smP4[1152];           // 8 b * 144 float4 = 18432 B
    __shared__ float smG[96];               // G[81] + wsum[9]
    __shared__ float red[256][5];           // block reduction, stride 5
    float* smP = (float*)smP4;

    const int tid = threadIdx.x;
    const int b_base4 = blockIdx.x * 1152;  // tile start in float4 units
    const float4* P4 = (const float4*)pillars;

#pragma unroll
    for (int i = tid; i < 1152; i += 256) smP4[i] = P4[b_base4 + i];
    if (tid < 90) smG[tid] = gw[tid];
    __syncthreads();

    const int lane = tid & 63;
    const int p = lane & 31;
    const int bsub = lane >> 5;
    const int b_local = (tid >> 6) * 2 + bsub;  // 0..7

    float v[18];
    {
        const float2* src = (const float2*)&smP[b_local * 576 + p * 18];
#pragma unroll
        for (int k = 0; k < 9; ++k) {
            const float2 t = src[k];
            v[2 * k] = t.x;
            v[2 * k + 1] = t.y;
        }
    }

    float d0 = 0.f, d1 = 0.f, q0 = 0.f, q1 = 0.f;
#pragma unroll
    for (int c = 0; c < 9; ++c) {
        const float wc = smG[81 + c];
        d0 = fmaf(wc, v[c], d0);
        d1 = fmaf(wc, v[9 + c], d1);
        float t0 = 0.f, t1 = 0.f;
#pragma unroll
        for (int c2 = 0; c2 < 9; ++c2) {
            const float g = smG[c * 9 + c2];
            t0 = fmaf(g, v[c2], t0);
            t1 = fmaf(g, v[9 + c2], t1);
        }
        q0 = fmaf(v[c], t0, q0);
        q1 = fmaf(v[9 + c], t1, q1);
    }

    red[tid][0] = d0; red[tid][1] = q0;
    red[tid][2] = d1; red[tid][3] = q1;
    __syncthreads();
    if (tid < 32) {  // p = tid; rows tid + 32k combine 4 waves x 2 bsub
        float s0 = 0.f, s1 = 0.f, s2 = 0.f, s3 = 0.f;
#pragma unroll
        for (int k = 0; k < 8; ++k) {
            s0 += red[tid + 32 * k][0];
            s1 += red[tid + 32 * k][1];
            s2 += red[tid + 32 * k][2];
            s3 += red[tid + 32 * k][3];
        }
        float* acc = acc8 + (blockIdx.x & 7) * 128;
        atomicAdd(&acc[(2 * tid) * 2], s0);
        atomicAdd(&acc[(2 * tid) * 2 + 1], s1);
        atomicAdd(&acc[(2 * tid + 1) * 2], s2);
        atomicAdd(&acc[(2 * tid + 1) * 2 + 1], s3);
    }
}

// One 8-b tile per block. LDS-staged pillars + padded W. BN finalize done
// per-block from the 8 shadow accumulators (L2-hot). Nontemporal dword
// stores, coalesced (lanes 0-31 -> b, 32-63 -> b+1: 2x128B segments).
__global__ __launch_bounds__(256) void pfn_main(const float* __restrict__ pillars,
                                                const float* __restrict__ W,
                                                const float* __restrict__ acc8,
                                                const float* __restrict__ gamma,
                                                const float* __restrict__ beta,
                                                float* __restrict__ out,
                                                float invBC, int ntiles) {
    __shared__ float4 smP4[1152];   // 18432 B
    __shared__ float smW[64 * 12];  // rows padded to 12 -> 16B-aligned
    __shared__ float smAB[128];     // a[64], bb[64]
    float* smP = (float*)smP4;

    const int tid = threadIdx.x;
    const int b_base4 = blockIdx.x * 1152;
    const float4* P4 = (const float4*)pillars;

#pragma unroll
    for (int i = tid; i < 1152; i += 256) smP4[i] = P4[b_base4 + i];
    for (int i = tid; i < 576; i += 256) smW[(i / 9) * 12 + (i % 9)] = W[i];
    if (tid < 64) {
        const int j = tid;
        float s1 = 0.f, s2 = 0.f;
#pragma unroll
        for (int s = 0; s < 8; ++s) {
            s1 += acc8[s * 128 + j * 2];
            s2 += acc8[s * 128 + j * 2 + 1];
        }
        const float mean = s1 * invBC;
        const float var = s2 * invBC - mean * mean;
        const float a = rsqrtf(var + EPS_BN) * gamma[j];
        smAB[j] = a;
        smAB[64 + j] = beta[j] - mean * a;
    }
    __syncthreads();

    const int lane = tid & 63;
    const int p = lane & 31;
    const int bsub = lane >> 5;
    const int b_local = (tid >> 6) * 2 + bsub;  // 0..7
    const int b = blockIdx.x * 8 + b_local;

    float v[18];
    {
        const float2* src = (const float2*)&smP[b_local * 576 + p * 18];
#pragma unroll
        for (int k = 0; k < 9; ++k) {
            const float2 t = src[k];
            v[2 * k] = t.x;
            v[2 * k + 1] = t.y;
        }
    }
    const float a0 = smAB[2 * p], a1 = smAB[2 * p + 1];
    const float b0 = smAB[64 + 2 * p], b1 = smAB[64 + 2 * p + 1];

    float* Ob = out + (size_t)b * 2048 + p;
#pragma unroll 8
    for (int o = 0; o < 64; ++o) {
        const float4 w0 = *(const float4*)&smW[o * 12];
        const float4 w1 = *(const float4*)&smW[o * 12 + 4];
        const float wc8 = smW[o * 12 + 8];
        float x0 = 0.f, x1 = 0.f;
        x0 = fmaf(w0.x, v[0], x0); x1 = fmaf(w0.x, v[9], x1);
        x0 = fmaf(w0.y, v[1], x0); x1 = fmaf(w0.y, v[10], x1);
        x0 = fmaf(w0.z, v[2], x0); x1 = fmaf(w0.z, v[11], x1);
        x0 = fmaf(w0.w, v[3], x0); x1 = fmaf(w0.w, v[12], x1);
        x0 = fmaf(w1.x, v[4], x0); x1 = fmaf(w1.x, v[13], x1);
        x0 = fmaf(w1.y, v[5], x0); x1 = fmaf(w1.y, v[14], x1);
        x0 = fmaf(w1.z, v[6], x0); x1 = fmaf(w1.z, v[15], x1);
        x0 = fmaf(w1.w, v[7], x0); x1 = fmaf(w1.w, v[16], x1);
        x0 = fmaf(wc8, v[8], x0);  x1 = fmaf(wc8, v[17], x1);
        const float r0 = fmaxf(fmaf(x0, a0, b0), 0.f);
        const float r1 = fmaxf(fmaf(x1, a1, b1), 0.f);
        __builtin_nontemporal_store(fmaxf(r0, r1), &Ob[o * 32]);
    }
}

extern "C" void kernel_launch(void* const* d_in, const int* in_sizes, int n_in,
                              void* d_out, int out_size, void* d_ws, size_t ws_size,
                              hipStream_t stream) {
    const float* pillars = (const float*)d_in[0];
    // d_in[1] = num_points_per_pillar: unused by the reference computation
    const float* W = (const float*)d_in[2];
    const float* gamma = (const float*)d_in[3];
    const float* beta = (const float*)d_in[4];
    float* out = (float*)d_out;
    float* ws = (float*)d_ws;

    const int B = in_sizes[0] / 576;  // 16384
    const int ntiles = B / 8;         // 2048

    pfn_prep<<<1, 64, 0, stream>>>(W, ws);
    pfn_stats<<<ntiles, 256, 0, stream>>>(pillars, ws, ws + 96, ntiles);
    pfn_main<<<ntiles, 256, 0, stream>>>(pillars, W, ws + 96, gamma, beta, out,
                                         1.0f / ((float)B * 64.0f), ntiles);
}

// Round 5
// 194.235 us; speedup vs baseline: 1.0547x; 1.0547x over previous
//
#include <hip/hip_runtime.h>

// PillarFeatureNet: linear(9->64, no bias) -> BN1d (training stats over B*Cout
// rows, P*N=64 cols) -> ReLU -> max over N.
//
// Round-5: r4's fused bodies as separate dispatches (cooperative launch failed
// to launch at 4 blocks/CU; unchecked error left d_out zeroed).
//  - stats: Gram trick (mean ~ dot(wsum,v), E[x^2] ~ v^T G v), 16-b LDS tiles
//  - main:  W held in REGISTERS (8 o-rows x 9 = 72/thread) -- r2/r3 re-read W
//           from LDS 192x/thread; now 24 LDS reads once. One 8-b tile/block,
//           one __syncthreads, BN finalize per-block from L2-hot accumulators.
//
// ws float layout:
//   [0,81)     G (9x9)      [81,90) wsum
//   [96,1120)  8 shadow copies x 128 accumulator floats
//              copy s, feature j, t(0=sum,1=sumsq): 96 + s*128 + j*2 + t

#define EPS_BN 1e-5f

__global__ __launch_bounds__(64) void pfn_prep(const float* __restrict__ W,
                                               float* __restrict__ ws) {
    __shared__ float prod[64][90];
    const int o = threadIdx.x;  // 0..63
    float w[9];
#pragma unroll
    for (int c = 0; c < 9; ++c) w[c] = W[o * 9 + c];
#pragma unroll
    for (int c = 0; c < 9; ++c)
#pragma unroll
        for (int c2 = 0; c2 < 9; ++c2) prod[o][c * 9 + c2] = w[c] * w[c2];
#pragma unroll
    for (int c = 0; c < 9; ++c) prod[o][81 + c] = w[c];
    // zero the 8 shadow accumulator copies: 1024 floats
#pragma unroll
    for (int k = 0; k < 16; ++k) ws[96 + o * 16 + k] = 0.f;
    __syncthreads();
    for (int col = o; col < 90; col += 64) {
        float s = 0.f;
        for (int r = 0; r < 64; ++r) s += prod[r][col];
        ws[col] = s;
    }
}

// 16 b per block (two 8-b LDS tile passes). Coalesced float4 staging.
__global__ __launch_bounds__(256) void pfn_stats(const float* __restrict__ pillars,
                                                 const float* __restrict__ gw,
                                                 float* __restrict__ acc8) {
    __shared__ float4 smP4[1152];  // 18432 B
    __shared__ float smG[96];      // G[81] + wsum[9]
    __shared__ float red[4][32][5];
    float* smP = (float*)smP4;

    const int tid = threadIdx.x;
    const int wv = tid >> 6;
    const int lane = tid & 63;
    const int p = lane & 31;
    const int bsub = lane >> 5;
    const int bl1 = wv * 2 + bsub;  // 0..7
    const float4* P4 = (const float4*)pillars;

    if (tid < 90) smG[tid] = gw[tid];

    float d0 = 0.f, d1 = 0.f, q0 = 0.f, q1 = 0.f;
    for (int pass = 0; pass < 2; ++pass) {
        const int base4 = (blockIdx.x * 16 + pass * 8) * 144;
        __syncthreads();
#pragma unroll
        for (int i = tid; i < 1152; i += 256) smP4[i] = P4[base4 + i];
        __syncthreads();
        float v[18];
        {
            const float2* src = (const float2*)&smP[bl1 * 576 + p * 18];
#pragma unroll
            for (int k = 0; k < 9; ++k) {
                const float2 t = src[k];
                v[2 * k] = t.x;
                v[2 * k + 1] = t.y;
            }
        }
#pragma unroll
        for (int c = 0; c < 9; ++c) {
            const float wc = smG[81 + c];
            d0 = fmaf(wc, v[c], d0);
            d1 = fmaf(wc, v[9 + c], d1);
            float t0 = 0.f, t1 = 0.f;
#pragma unroll
            for (int c2 = 0; c2 < 9; ++c2) {
                const float g = smG[c * 9 + c2];
                t0 = fmaf(g, v[c2], t0);
                t1 = fmaf(g, v[9 + c2], t1);
            }
            q0 = fmaf(v[c], t0, q0);
            q1 = fmaf(v[9 + c], t1, q1);
        }
    }
    // fold the two bsub halves (same p, different b)
    d0 += __shfl_xor(d0, 32); q0 += __shfl_xor(q0, 32);
    d1 += __shfl_xor(d1, 32); q1 += __shfl_xor(q1, 32);
    __syncthreads();
    if (lane < 32) {
        red[wv][p][0] = d0; red[wv][p][1] = q0;
        red[wv][p][2] = d1; red[wv][p][3] = q1;
    }
    __syncthreads();
    if (tid < 32) {
        float s0 = 0.f, s1 = 0.f, s2 = 0.f, s3 = 0.f;
#pragma unroll
        for (int w = 0; w < 4; ++w) {
            s0 += red[w][tid][0]; s1 += red[w][tid][1];
            s2 += red[w][tid][2]; s3 += red[w][tid][3];
        }
        float* acc = acc8 + (blockIdx.x & 7) * 128;
        atomicAdd(&acc[(2 * tid) * 2], s0);
        atomicAdd(&acc[(2 * tid) * 2 + 1], s1);
        atomicAdd(&acc[(2 * tid + 1) * 2], s2);
        atomicAdd(&acc[(2 * tid + 1) * 2 + 1], s3);
    }
}

// One 8-b tile per block; thread (g=tid>>5, p=tid&31) owns o in [8g,8g+8).
__global__ __launch_bounds__(256) void pfn_main(const float* __restrict__ pillars,
                                                const float* __restrict__ W,
                                                const float* __restrict__ acc8,
                                                const float* __restrict__ gamma,
                                                const float* __restrict__ beta,
                                                float* __restrict__ out,
                                                float invBC) {
    __shared__ float4 smP4[1152];   // 18432 B
    __shared__ float smW[64 * 12];  // rows padded to 12 (16B-aligned)
    __shared__ float smAB[128];     // a[64], bb[64]
    float* smP = (float*)smP4;

    const int tid = threadIdx.x;
    const float4* P4 = (const float4*)pillars;

    for (int i = tid; i < 576; i += 256) smW[(i / 9) * 12 + (i % 9)] = W[i];
    {
        const int base4 = blockIdx.x * 1152;
#pragma unroll
        for (int i = tid; i < 1152; i += 256) smP4[i] = P4[base4 + i];
    }
    if (tid < 64) {
        float s1 = 0.f, s2 = 0.f;
#pragma unroll
        for (int s = 0; s < 8; ++s) {
            s1 += acc8[s * 128 + tid * 2];
            s2 += acc8[s * 128 + tid * 2 + 1];
        }
        const float mean = s1 * invBC;
        const float var = s2 * invBC - mean * mean;
        const float a = rsqrtf(var + EPS_BN) * gamma[tid];
        smAB[tid] = a;
        smAB[64 + tid] = beta[tid] - mean * a;
    }
    __syncthreads();

    const int g = tid >> 5;   // o-group: o in [8g, 8g+8)
    const int p = tid & 31;
    float wr[72];
#pragma unroll
    for (int k = 0; k < 8; ++k) {
        const int o = g * 8 + k;
        const float4 wa = *(const float4*)&smW[o * 12];
        const float4 wb = *(const float4*)&smW[o * 12 + 4];
        wr[k * 9 + 0] = wa.x; wr[k * 9 + 1] = wa.y;
        wr[k * 9 + 2] = wa.z; wr[k * 9 + 3] = wa.w;
        wr[k * 9 + 4] = wb.x; wr[k * 9 + 5] = wb.y;
        wr[k * 9 + 6] = wb.z; wr[k * 9 + 7] = wb.w;
        wr[k * 9 + 8] = smW[o * 12 + 8];
    }
    const float a0 = smAB[2 * p], a1 = smAB[2 * p + 1];
    const float bb0 = smAB[64 + 2 * p], bb1 = smAB[64 + 2 * p + 1];

    float* Ob0 = out + (size_t)blockIdx.x * 16384 + g * 256 + p;
#pragma unroll 2
    for (int bl = 0; bl < 8; ++bl) {
        float vs0[9], vs1[9];
        {
            const float2* src = (const float2*)&smP[bl * 576 + p * 18];
#pragma unroll
            for (int k = 0; k < 4; ++k) {  // n=0, c = 2k, 2k+1
                const float2 t = src[k];
                vs0[2 * k] = t.x * a0;
                vs0[2 * k + 1] = t.y * a0;
            }
            {
                const float2 t = src[4];   // c=8 (n=0), c=0 (n=1)
                vs0[8] = t.x * a0;
                vs1[0] = t.y * a1;
            }
#pragma unroll
            for (int k = 0; k < 4; ++k) {  // n=1, c = 1+2k, 2+2k
                const float2 t = src[5 + k];
                vs1[1 + 2 * k] = t.x * a1;
                vs1[2 + 2 * k] = t.y * a1;
            }
        }
        float* Ob = Ob0 + bl * 2048;
#pragma unroll
        for (int k = 0; k < 8; ++k) {
            float x0 = bb0, x1 = bb1;
#pragma unroll
            for (int c = 0; c < 9; ++c) {
                x0 = fmaf(wr[k * 9 + c], vs0[c], x0);
                x1 = fmaf(wr[k * 9 + c], vs1[c], x1);
            }
            __builtin_nontemporal_store(fmaxf(fmaxf(x0, x1), 0.f), &Ob[k * 32]);
        }
    }
}

extern "C" void kernel_launch(void* const* d_in, const int* in_sizes, int n_in,
                              void* d_out, int out_size, void* d_ws, size_t ws_size,
                              hipStream_t stream) {
    const float* pillars = (const float*)d_in[0];
    // d_in[1] = num_points_per_pillar: unused by the reference computation
    const float* W = (const float*)d_in[2];
    const float* gamma = (const float*)d_in[3];
    const float* beta = (const float*)d_in[4];
    float* out = (float*)d_out;
    float* ws = (float*)d_ws;

    const int B = in_sizes[0] / 576;  // 16384
    const float invBC = 1.0f / ((float)B * 64.0f);

    pfn_prep<<<1, 64, 0, stream>>>(W, ws);
    pfn_stats<<<B / 16, 256, 0, stream>>>(pillars, ws, ws + 96);
    pfn_main<<<B / 8, 256, 0, stream>>>(pillars, W, ws + 96, gamma, beta, out,
                                        invBC);
}

// Round 6
// 192.454 us; speedup vs baseline: 1.0644x; 1.0093x over previous
//
#include <hip/hip_runtime.h>

// PillarFeatureNet: linear(9->64, no bias) -> BN1d (training stats over B*Cout
// rows, P*N=64 cols) -> ReLU -> max over N.
//
// Round-6: best-of-both recombination based on cross-round evidence:
//   r2 (direct global reads, LDS-W)   187.6 us
//   r3 (LDS-staged reads,  LDS-W)     204.9 us  <- staging regressed
//   r5 (LDS-staged reads,  reg-W)     194.2 us  <- reg-W recovered some
// => r6: direct global reads (L1 broadcasts across the 8 waves sharing each
//    2304B window; no 4-way-conflicted ds_read_b64, no extra syncs) + reg-W
//    epilogue + per-block BN finalize + plain stores.
//
// ws float layout:
//   [0,81)     G (9x9)      [81,90) wsum
//   [96,1120)  8 shadow copies x 128 accumulator floats
//              copy s, feature j, t(0=sum,1=sumsq): 96 + s*128 + j*2 + t

#define EPS_BN 1e-5f

__global__ __launch_bounds__(64) void pfn_prep(const float* __restrict__ W,
                                               float* __restrict__ ws) {
    __shared__ float prod[64][90];
    const int o = threadIdx.x;  // 0..63
    float w[9];
#pragma unroll
    for (int c = 0; c < 9; ++c) w[c] = W[o * 9 + c];
#pragma unroll
    for (int c = 0; c < 9; ++c)
#pragma unroll
        for (int c2 = 0; c2 < 9; ++c2) prod[o][c * 9 + c2] = w[c] * w[c2];
#pragma unroll
    for (int c = 0; c < 9; ++c) prod[o][81 + c] = w[c];
    // zero the 8 shadow accumulator copies: 1024 floats
#pragma unroll
    for (int k = 0; k < 16; ++k) ws[96 + o * 16 + k] = 0.f;
    __syncthreads();
    for (int col = o; col < 90; col += 64) {
        float s = 0.f;
        for (int r = 0; r < 64; ++r) s += prod[r][col];
        ws[col] = s;
    }
}

// 1024 blocks; wave wv handles pillar-pairs pr = blk*4+wv and +4096 (16 b/blk).
// Direct global float2 reads (no LDS staging).
__global__ __launch_bounds__(256) void pfn_stats(const float* __restrict__ pillars,
                                                 const float* __restrict__ gw,
                                                 float* __restrict__ acc8) {
    __shared__ float smG[96];  // G[81] + wsum[9]
    __shared__ float red[4][32][5];

    const int tid = threadIdx.x;
    const int wv = tid >> 6;
    const int lane = tid & 63;
    const int p = lane & 31;
    const int bsub = lane >> 5;

    if (tid < 90) smG[tid] = gw[tid];
    __syncthreads();

    float d0 = 0.f, d1 = 0.f, q0 = 0.f, q1 = 0.f;
#pragma unroll
    for (int it = 0; it < 2; ++it) {
        const int pr = blockIdx.x * 4 + wv + it * 4096;
        const int b = pr * 2 + bsub;
        const float2* src = (const float2*)(pillars + (size_t)b * 576 + p * 18);
        float v[18];
#pragma unroll
        for (int k = 0; k < 9; ++k) {
            const float2 t = src[k];
            v[2 * k] = t.x;
            v[2 * k + 1] = t.y;
        }
#pragma unroll
        for (int c = 0; c < 9; ++c) {
            const float wc = smG[81 + c];
            d0 = fmaf(wc, v[c], d0);
            d1 = fmaf(wc, v[9 + c], d1);
            float t0 = 0.f, t1 = 0.f;
#pragma unroll
            for (int c2 = 0; c2 < 9; ++c2) {
                const float g = smG[c * 9 + c2];
                t0 = fmaf(g, v[c2], t0);
                t1 = fmaf(g, v[9 + c2], t1);
            }
            q0 = fmaf(v[c], t0, q0);
            q1 = fmaf(v[9 + c], t1, q1);
        }
    }
    // fold the two bsub halves (same p, different b)
    d0 += __shfl_xor(d0, 32); q0 += __shfl_xor(q0, 32);
    d1 += __shfl_xor(d1, 32); q1 += __shfl_xor(q1, 32);
    if (lane < 32) {
        red[wv][p][0] = d0; red[wv][p][1] = q0;
        red[wv][p][2] = d1; red[wv][p][3] = q1;
    }
    __syncthreads();
    if (tid < 32) {
        float s0 = 0.f, s1 = 0.f, s2 = 0.f, s3 = 0.f;
#pragma unroll
        for (int w = 0; w < 4; ++w) {
            s0 += red[w][tid][0]; s1 += red[w][tid][1];
            s2 += red[w][tid][2]; s3 += red[w][tid][3];
        }
        float* acc = acc8 + (blockIdx.x & 7) * 128;
        atomicAdd(&acc[(2 * tid) * 2], s0);
        atomicAdd(&acc[(2 * tid) * 2 + 1], s1);
        atomicAdd(&acc[(2 * tid + 1) * 2], s2);
        atomicAdd(&acc[(2 * tid + 1) * 2 + 1], s3);
    }
}

// 2048 blocks; 8 b per block. Thread (g=tid>>5, p=tid&31) owns o in [8g,8g+8),
// W held in registers, pillars read directly from global (L1-broadcast across
// the 8 waves reading the same 2304B window per bl).
__global__ __launch_bounds__(256) void pfn_main(const float* __restrict__ pillars,
                                                const float* __restrict__ W,
                                                const float* __restrict__ acc8,
                                                const float* __restrict__ gamma,
                                                const float* __restrict__ beta,
                                                float* __restrict__ out,
                                                float invBC) {
    __shared__ float smW[64 * 12];  // rows padded to 12 (16B-aligned)
    __shared__ float smAB[128];     // a[64], bb[64]

    const int tid = threadIdx.x;
    for (int i = tid; i < 576; i += 256) smW[(i / 9) * 12 + (i % 9)] = W[i];
    if (tid < 64) {
        float s1 = 0.f, s2 = 0.f;
#pragma unroll
        for (int s = 0; s < 8; ++s) {
            s1 += acc8[s * 128 + tid * 2];
            s2 += acc8[s * 128 + tid * 2 + 1];
        }
        const float mean = s1 * invBC;
        const float var = s2 * invBC - mean * mean;
        const float a = rsqrtf(var + EPS_BN) * gamma[tid];
        smAB[tid] = a;
        smAB[64 + tid] = beta[tid] - mean * a;
    }
    __syncthreads();

    const int g = tid >> 5;   // o-group: o in [8g, 8g+8)
    const int p = tid & 31;
    float wr[72];
#pragma unroll
    for (int k = 0; k < 8; ++k) {
        const int o = g * 8 + k;
        const float4 wa = *(const float4*)&smW[o * 12];
        const float4 wb = *(const float4*)&smW[o * 12 + 4];
        wr[k * 9 + 0] = wa.x; wr[k * 9 + 1] = wa.y;
        wr[k * 9 + 2] = wa.z; wr[k * 9 + 3] = wa.w;
        wr[k * 9 + 4] = wb.x; wr[k * 9 + 5] = wb.y;
        wr[k * 9 + 6] = wb.z; wr[k * 9 + 7] = wb.w;
        wr[k * 9 + 8] = smW[o * 12 + 8];
    }
    const float a0 = smAB[2 * p], a1 = smAB[2 * p + 1];
    const float bb0 = smAB[64 + 2 * p], bb1 = smAB[64 + 2 * p + 1];

    const float* Pb0 = pillars + (size_t)blockIdx.x * 8 * 576 + p * 18;
    float* Ob0 = out + (size_t)blockIdx.x * 16384 + g * 256 + p;
#pragma unroll 2
    for (int bl = 0; bl < 8; ++bl) {
        float vs0[9], vs1[9];
        {
            const float2* src = (const float2*)(Pb0 + bl * 576);
#pragma unroll
            for (int k = 0; k < 4; ++k) {  // n=0, c = 2k, 2k+1
                const float2 t = src[k];
                vs0[2 * k] = t.x * a0;
                vs0[2 * k + 1] = t.y * a0;
            }
            {
                const float2 t = src[4];   // c=8 (n=0), c=0 (n=1)
                vs0[8] = t.x * a0;
                vs1[0] = t.y * a1;
            }
#pragma unroll
            for (int k = 0; k < 4; ++k) {  // n=1, c = 1+2k, 2+2k
                const float2 t = src[5 + k];
                vs1[1 + 2 * k] = t.x * a1;
                vs1[2 + 2 * k] = t.y * a1;
            }
        }
        float* Ob = Ob0 + bl * 2048;
#pragma unroll
        for (int k = 0; k < 8; ++k) {
            float x0 = bb0, x1 = bb1;
#pragma unroll
            for (int c = 0; c < 9; ++c) {
                x0 = fmaf(wr[k * 9 + c], vs0[c], x0);
                x1 = fmaf(wr[k * 9 + c], vs1[c], x1);
            }
            Ob[k * 32] = fmaxf(fmaxf(x0, x1), 0.f);
        }
    }
}

extern "C" void kernel_launch(void* const* d_in, const int* in_sizes, int n_in,
                              void* d_out, int out_size, void* d_ws, size_t ws_size,
                              hipStream_t stream) {
    const float* pillars = (const float*)d_in[0];
    // d_in[1] = num_points_per_pillar: unused by the reference computation
    const float* W = (const float*)d_in[2];
    const float* gamma = (const float*)d_in[3];
    const float* beta = (const float*)d_in[4];
    float* out = (float*)d_out;
    float* ws = (float*)d_ws;

    const int B = in_sizes[0] / 576;  // 16384
    const float invBC = 1.0f / ((float)B * 64.0f);

    pfn_prep<<<1, 64, 0, stream>>>(W, ws);
    pfn_stats<<<B / 16, 256, 0, stream>>>(pillars, ws, ws + 96);
    pfn_main<<<B / 8, 256, 0, stream>>>(pillars, W, ws + 96, gamma, beta, out,
                                        invBC);
}

// Round 7
// 189.717 us; speedup vs baseline: 1.0798x; 1.0144x over previous
//
#include <hip/hip_runtime.h>

// PillarFeatureNet: linear(9->64, no bias) -> BN1d (training stats over B*Cout
// rows, P*N=64 cols) -> ReLU -> max over N.
//
// Round-7: transposed LDS staging smT[b][c*64 + j] (j = p*2+n):
//  - global side: perfectly coalesced float4 loads (r6 direct reads touched
//    ~72 cache lines per wave-load -> serialized L1 line accesses)
//  - LDS consume side: lane-consecutive -> conflict-free (r3/r5 staging had
//    4-way conflicts: p-stride 18 floats, gcd(18,32)=2)
// prep folded into stats (saves a dispatch); acc8 zeroed by 4KB memset.
//
// ws float layout: [0,1024) 8 shadow copies x 128 floats
//                  copy s, feature j, t(0=sum,1=sumsq): s*128 + j*2 + t

#define EPS_BN 1e-5f

// 1024 blocks, 16 b each (two 8-b transposed tiles). G computed in-block.
__global__ __launch_bounds__(256) void pfn_stats(const float* __restrict__ pillars,
                                                 const float* __restrict__ W,
                                                 float* __restrict__ acc8) {
    __shared__ float smS[5760];     // phase0: prod[64][90]; phase1: smT[8*576]
    __shared__ float smG[96];       // G[81] + wsum[9] (cols 81..89)
    __shared__ float red[4][64][2];

    const int tid = threadIdx.x;
    const int wv = tid >> 6;
    const int lane = tid & 63;
    const float4* P4 = (const float4*)pillars;

    // ---- phase 0: G = W^T W, wsum = col-sums of W ----
    if (tid < 64) {
        float w[9];
#pragma unroll
        for (int c = 0; c < 9; ++c) w[c] = W[tid * 9 + c];
        float* row = &smS[tid * 90];
#pragma unroll
        for (int c = 0; c < 9; ++c)
#pragma unroll
            for (int c2 = 0; c2 < 9; ++c2) row[c * 9 + c2] = w[c] * w[c2];
#pragma unroll
        for (int c = 0; c < 9; ++c) row[81 + c] = w[c];
    }
    __syncthreads();
    if (tid < 90) {
        float s = 0.f;
        for (int r = 0; r < 64; ++r) s += smS[r * 90 + tid];
        smG[tid] = s;
    }

    // ---- phase 1: two 8-b transposed tiles ----
    float dacc = 0.f, qacc = 0.f;
    for (int pass = 0; pass < 2; ++pass) {
        __syncthreads();  // protects smS (phase0 readers / previous tile)
        const int base4 = (blockIdx.x * 16 + pass * 8) * 144;
        for (int i = tid; i < 1152; i += 256) {
            const float4 g4 = P4[base4 + i];
            const float comp[4] = {g4.x, g4.y, g4.z, g4.w};
            const int f0 = 4 * i;
#pragma unroll
            for (int t = 0; t < 4; ++t) {
                const int ff = f0 + t;
                const int bl = ff / 576;
                const int r = ff - bl * 576;
                const int j = r / 9;
                const int c = r - j * 9;
                smS[bl * 576 + c * 64 + j] = comp[t];
            }
        }
        __syncthreads();
#pragma unroll
        for (int bb = 0; bb < 2; ++bb) {
            const float* src = &smS[(wv * 2 + bb) * 576];
            float v[9];
#pragma unroll
            for (int c = 0; c < 9; ++c) v[c] = src[c * 64 + lane];  // conflict-free
            float d = 0.f, q = 0.f;
#pragma unroll
            for (int c = 0; c < 9; ++c) {
                d = fmaf(smG[81 + c], v[c], d);
                float t = 0.f;
#pragma unroll
                for (int c2 = 0; c2 < 9; ++c2) t = fmaf(smG[c * 9 + c2], v[c2], t);
                q = fmaf(v[c], t, q);
            }
            dacc += d;
            qacc += q;
        }
    }
    red[wv][lane][0] = dacc;
    red[wv][lane][1] = qacc;
    __syncthreads();
    if (tid < 64) {
        float sd = 0.f, sq = 0.f;
#pragma unroll
        for (int w = 0; w < 4; ++w) {
            sd += red[w][tid][0];
            sq += red[w][tid][1];
        }
        float* acc = acc8 + (blockIdx.x & 7) * 128;
        atomicAdd(&acc[tid * 2], sd);
        atomicAdd(&acc[tid * 2 + 1], sq);
    }
}

// 2048 blocks, 8 b each. Transposed tile; thread (g=tid>>5, p=tid&31) owns
// o in [8g,8g+8) with W in registers; BN finalize per-block (acc8 L2-hot).
__global__ __launch_bounds__(256) void pfn_main(const float* __restrict__ pillars,
                                                const float* __restrict__ W,
                                                const float* __restrict__ acc8,
                                                const float* __restrict__ gamma,
                                                const float* __restrict__ beta,
                                                float* __restrict__ out,
                                                float invBC) {
    __shared__ float smT[8 * 576];  // 18432 B, transposed: [b][c*64 + j]
    __shared__ float smW[64 * 12];  // rows padded to 12 (16B-aligned)
    __shared__ float smAB[128];     // a[64], bb[64]

    const int tid = threadIdx.x;
    const float4* P4 = (const float4*)pillars;

    {   // transposed staging, coalesced float4 global loads
        const int base4 = blockIdx.x * 1152;
        for (int i = tid; i < 1152; i += 256) {
            const float4 g4 = P4[base4 + i];
            const float comp[4] = {g4.x, g4.y, g4.z, g4.w};
            const int f0 = 4 * i;
#pragma unroll
            for (int t = 0; t < 4; ++t) {
                const int ff = f0 + t;
                const int bl = ff / 576;
                const int r = ff - bl * 576;
                const int j = r / 9;
                const int c = r - j * 9;
                smT[bl * 576 + c * 64 + j] = comp[t];
            }
        }
    }
    for (int i = tid; i < 576; i += 256) smW[(i / 9) * 12 + (i % 9)] = W[i];
    if (tid < 64) {
        float s1 = 0.f, s2 = 0.f;
#pragma unroll
        for (int s = 0; s < 8; ++s) {
            s1 += acc8[s * 128 + tid * 2];
            s2 += acc8[s * 128 + tid * 2 + 1];
        }
        const float mean = s1 * invBC;
        const float var = s2 * invBC - mean * mean;
        const float a = rsqrtf(var + EPS_BN) * gamma[tid];
        smAB[tid] = a;
        smAB[64 + tid] = beta[tid] - mean * a;
    }
    __syncthreads();

    const int g = tid >> 5;  // o-group: o in [8g, 8g+8)
    const int p = tid & 31;
    float wr[72];
#pragma unroll
    for (int k = 0; k < 8; ++k) {
        const int o = g * 8 + k;
        const float4 wa = *(const float4*)&smW[o * 12];
        const float4 wb = *(const float4*)&smW[o * 12 + 4];
        wr[k * 9 + 0] = wa.x; wr[k * 9 + 1] = wa.y;
        wr[k * 9 + 2] = wa.z; wr[k * 9 + 3] = wa.w;
        wr[k * 9 + 4] = wb.x; wr[k * 9 + 5] = wb.y;
        wr[k * 9 + 6] = wb.z; wr[k * 9 + 7] = wb.w;
        wr[k * 9 + 8] = smW[o * 12 + 8];
    }
    const float a0 = smAB[2 * p], a1 = smAB[2 * p + 1];
    const float bb0 = smAB[64 + 2 * p], bb1 = smAB[64 + 2 * p + 1];

    float* Ob0 = out + (size_t)blockIdx.x * 16384 + g * 256 + p;
#pragma unroll 2
    for (int bl = 0; bl < 8; ++bl) {
        // conflict-free ds_read_b64: lanes read consecutive (2p,2p+1) pairs;
        // upper half-wave duplicates addresses -> same-address broadcast
        float vs0[9], vs1[9];
        {
            const float* src = &smT[bl * 576];
#pragma unroll
            for (int c = 0; c < 9; ++c) {
                const float2 t = *(const float2*)&src[c * 64 + 2 * p];
                vs0[c] = t.x * a0;  // n=0
                vs1[c] = t.y * a1;  // n=1
            }
        }
        float* Ob = Ob0 + bl * 2048;
#pragma unroll
        for (int k = 0; k < 8; ++k) {
            float x0 = bb0, x1 = bb1;
#pragma unroll
            for (int c = 0; c < 9; ++c) {
                x0 = fmaf(wr[k * 9 + c], vs0[c], x0);
                x1 = fmaf(wr[k * 9 + c], vs1[c], x1);
            }
            Ob[k * 32] = fmaxf(fmaxf(x0, x1), 0.f);
        }
    }
}

extern "C" void kernel_launch(void* const* d_in, const int* in_sizes, int n_in,
                              void* d_out, int out_size, void* d_ws, size_t ws_size,
                              hipStream_t stream) {
    const float* pillars = (const float*)d_in[0];
    // d_in[1] = num_points_per_pillar: unused by the reference computation
    const float* W = (const float*)d_in[2];
    const float* gamma = (const float*)d_in[3];
    const float* beta = (const float*)d_in[4];
    float* out = (float*)d_out;
    float* ws = (float*)d_ws;

    const int B = in_sizes[0] / 576;  // 16384
    const float invBC = 1.0f / ((float)B * 64.0f);

    hipMemsetAsync(ws, 0, 1024 * sizeof(float), stream);
    pfn_stats<<<B / 16, 256, 0, stream>>>(pillars, W, ws);
    pfn_main<<<B / 8, 256, 0, stream>>>(pillars, W, ws, gamma, beta, out, invBC);
}